// Round 2
// baseline (19456.438 us; speedup 1.0000x reference)
//
#include <hip/hip_runtime.h>
#include <hip/hip_bf16.h>
#include <math.h>

#define BB 64
#define PP 196
#define CC 2048
#define DD 512
#define AA 512
#define EE 512
#define VV 30000
#define LL 32
#define TT 31

// ---------- setup kernels ----------

__global__ __launch_bounds__(256) void k_mean(const float* __restrict__ enc, float* __restrict__ mean) {
    int b = blockIdx.x;
    int c = blockIdx.y * 256 + threadIdx.x;
    const float* base = enc + (size_t)b * PP * CC + c;
    float s = 0.f;
    for (int p = 0; p < PP; ++p) s += base[(size_t)p * CC];
    mean[(size_t)b * CC + c] = s * (1.0f / PP);
}

__global__ void k_sort(const int* __restrict__ text, const int* __restrict__ lens,
                       int* __restrict__ idx, int* __restrict__ tlen, int* __restrict__ ts,
                       float* __restrict__ out_text,
                       float* __restrict__ out_tlen,
                       float* __restrict__ out_idx) {
    int j = threadIdx.x;  // 64 threads
    __shared__ int key[BB];
    __shared__ int sidx[BB];
    key[j] = lens[j];  // lens is (B,1)
    __syncthreads();
    int kj = key[j];
    int pos = 0;
    for (int q = 0; q < BB; ++q) {
        int kq = key[q];
        if (kq > kj || (kq == kj && q < j)) pos++;
    }
    sidx[pos] = j;
    __syncthreads();
    int src = sidx[j];
    idx[j] = src;
    int tl = key[src] - 1;
    tlen[j] = tl;
    out_idx[j] = (float)src;
    out_tlen[j] = (float)tl;
    for (int l = 0; l < LL; ++l) {
        int tok = text[src * LL + l];
        ts[j * LL + l] = tok;
        out_text[j * LL + l] = (float)tok;
    }
}

__global__ __launch_bounds__(256) void k_init(const float* __restrict__ mean,
                                              const float* __restrict__ Wh, const float* __restrict__ bh,
                                              const float* __restrict__ Wc, const float* __restrict__ bc,
                                              float* __restrict__ hT, float* __restrict__ cT) {
    int b = blockIdx.x;
    int d = blockIdx.y * 256 + threadIdx.x;
    const float* m = mean + (size_t)b * CC;
    float ah = 0.f, ac = 0.f;
    for (int k = 0; k < CC; ++k) {
        float mv = m[k];
        ah = fmaf(mv, Wh[(size_t)k * DD + d], ah);
        ac = fmaf(mv, Wc[(size_t)k * DD + d], ac);
    }
    hT[(size_t)d * BB + b] = ah + bh[d];
    cT[(size_t)d * BB + b] = ac + bc[d];
}

// en_attn = img_s @ W_en + b_en ; grid (64*14, 2), block 256; 14 p-rows per block
__global__ __launch_bounds__(256) void k_enattn(const float* __restrict__ enc, const int* __restrict__ idx,
                                                const float* __restrict__ W, const float* __restrict__ bias,
                                                float* __restrict__ en) {
    int b = blockIdx.x / 14;
    int p0 = (blockIdx.x % 14) * 14;
    int n = blockIdx.y * 256 + threadIdx.x;
    const float* img = enc + (size_t)idx[b] * PP * CC + (size_t)p0 * CC;
    float acc[14];
#pragma unroll
    for (int i = 0; i < 14; ++i) acc[i] = 0.f;
    for (int k = 0; k < CC; ++k) {
        float w = W[(size_t)k * AA + n];
#pragma unroll
        for (int i = 0; i < 14; ++i) acc[i] = fmaf(img[(size_t)i * CC + k], w, acc[i]);
    }
    float bv = bias[n];
    for (int i = 0; i < 14; ++i)
        en[((size_t)b * PP + p0 + i) * AA + n] = acc[i] + bv;
}

// ---------- per-step kernels ----------

// de = h @ W_de + b_de ; grid 8 blocks x 512 threads, 8 batches per block
__global__ __launch_bounds__(512) void k_de(const float* __restrict__ hT, const float* __restrict__ W,
                                            const float* __restrict__ bias, float* __restrict__ de) {
    int d = threadIdx.x;
    int b0 = blockIdx.x * 8;
    float acc[8] = {0.f, 0.f, 0.f, 0.f, 0.f, 0.f, 0.f, 0.f};
    for (int k = 0; k < DD; ++k) {
        float w = W[(size_t)k * AA + d];
        const float* hr = hT + (size_t)k * BB + b0;
#pragma unroll
        for (int i = 0; i < 8; ++i) acc[i] = fmaf(hr[i], w, acc[i]);
    }
    float bv = bias[d];
    for (int i = 0; i < 8; ++i) de[(size_t)(b0 + i) * AA + d] = acc[i] + bv;
}

// scores + softmax -> alpha (ws) and attention output; one block per b
__global__ __launch_bounds__(256) void k_score(const float* __restrict__ en, const float* __restrict__ de,
                                               const float* __restrict__ Wat, const float* __restrict__ bat,
                                               const int* __restrict__ tlen, int t,
                                               float* __restrict__ alpha, float* __restrict__ out_attn) {
    int b = blockIdx.x;
    int tid = threadIdx.x;
    __shared__ float deL[AA];
    __shared__ float watL[AA];
    __shared__ float red[256];
    deL[tid] = de[(size_t)b * AA + tid];
    deL[tid + 256] = de[(size_t)b * AA + 256 + tid];
    watL[tid] = Wat[tid];
    watL[tid + 256] = Wat[tid + 256];
    __syncthreads();
    float s = 0.f;
    if (tid < PP) {
        const float4* er4 = (const float4*)(en + ((size_t)b * PP + tid) * AA);
        for (int a4 = 0; a4 < AA / 4; ++a4) {
            float4 v = er4[a4];
            float v0 = fmaxf(v.x + deL[4 * a4 + 0], 0.f);
            float v1 = fmaxf(v.y + deL[4 * a4 + 1], 0.f);
            float v2 = fmaxf(v.z + deL[4 * a4 + 2], 0.f);
            float v3 = fmaxf(v.w + deL[4 * a4 + 3], 0.f);
            s = fmaf(v0, watL[4 * a4 + 0], s);
            s = fmaf(v1, watL[4 * a4 + 1], s);
            s = fmaf(v2, watL[4 * a4 + 2], s);
            s = fmaf(v3, watL[4 * a4 + 3], s);
        }
        s += bat[0];
    }
    // max reduce
    red[tid] = (tid < PP) ? s : -3.4e38f;
    __syncthreads();
    for (int st = 128; st > 0; st >>= 1) {
        if (tid < st) red[tid] = fmaxf(red[tid], red[tid + st]);
        __syncthreads();
    }
    float m = red[0];
    __syncthreads();
    float e = (tid < PP) ? expf(s - m) : 0.f;
    red[tid] = e;
    __syncthreads();
    for (int st = 128; st > 0; st >>= 1) {
        if (tid < st) red[tid] += red[tid + st];
        __syncthreads();
    }
    float inv = 1.0f / red[0];
    if (tid < PP) {
        float al = e * inv;
        alpha[(size_t)b * PP + tid] = al;
        bool act = t < tlen[b];
        out_attn[((size_t)b * TT + t) * PP + tid] = act ? al : 0.f;
    }
}

// ctx[b,c] = sum_p alpha[b,p] * img_s[b,p,c] ; grid (64, 8) block 256
__global__ __launch_bounds__(256) void k_ctx(const float* __restrict__ enc, const int* __restrict__ idx,
                                             const float* __restrict__ alpha, float* __restrict__ ctx) {
    int b = blockIdx.x;
    int c0 = blockIdx.y * 256 + threadIdx.x;
    const float* img = enc + (size_t)idx[b] * PP * CC;
    __shared__ float al[PP];
    if (threadIdx.x < PP) al[threadIdx.x] = alpha[(size_t)b * PP + threadIdx.x];
    __syncthreads();
    float a = 0.f;
    for (int p = 0; p < PP; ++p) a = fmaf(al[p], img[(size_t)p * CC + c0], a);
    ctx[(size_t)b * CC + c0] = a;
}

// gate = sigmoid(h@W_gate+b) ; xT[j] = ctx*gate (transposed) ; grid (8,8) block 256
__global__ __launch_bounds__(256) void k_gatex(const float* __restrict__ hT, const float* __restrict__ Wg,
                                               const float* __restrict__ bg, const float* __restrict__ ctx,
                                               float* __restrict__ xT) {
    int j = blockIdx.y * 256 + threadIdx.x;
    int b0 = blockIdx.x * 8;
    float acc[8] = {0.f, 0.f, 0.f, 0.f, 0.f, 0.f, 0.f, 0.f};
    for (int k = 0; k < DD; ++k) {
        float w = Wg[(size_t)k * CC + j];
        const float* hr = hT + (size_t)k * BB + b0;
#pragma unroll
        for (int i = 0; i < 8; ++i) acc[i] = fmaf(hr[i], w, acc[i]);
    }
    float bv = bg[j];
#pragma unroll
    for (int i = 0; i < 8; ++i) {
        float gt = 1.f / (1.f + expf(-(acc[i] + bv)));
        xT[(size_t)j * BB + b0 + i] = ctx[(size_t)(b0 + i) * CC + j] * gt;
    }
}

// xT[2048+e][b] = embed[ts[b][t]][e]
__global__ __launch_bounds__(256) void k_emb(const float* __restrict__ embed, const int* __restrict__ ts,
                                             int t, float* __restrict__ xT) {
    int gid = blockIdx.x * 256 + threadIdx.x;  // < 64*512
    int e = gid >> 6;
    int b = gid & 63;
    int tok = ts[b * LL + t];
    xT[(size_t)(CC + e) * BB + b] = embed[(size_t)tok * EE + e];
}

// gates = x@W_ih + h@W_hh + b_ih + b_hh ; grid (16, 8) block 256, 4 batches per block
__global__ __launch_bounds__(256) void k_gates(const float* __restrict__ xT, const float* __restrict__ Wih,
                                               const float* __restrict__ bih, const float* __restrict__ hT,
                                               const float* __restrict__ Whh, const float* __restrict__ bhh,
                                               float* __restrict__ gates) {
    int n = blockIdx.y * 256 + threadIdx.x;
    int b0 = blockIdx.x * 4;
    float acc[4] = {0.f, 0.f, 0.f, 0.f};
    for (int k = 0; k < CC + EE; ++k) {
        float w = Wih[(size_t)k * 2048 + n];
        const float* xr = xT + (size_t)k * BB + b0;
#pragma unroll
        for (int i = 0; i < 4; ++i) acc[i] = fmaf(xr[i], w, acc[i]);
    }
    for (int k = 0; k < DD; ++k) {
        float w = Whh[(size_t)k * 2048 + n];
        const float* hr = hT + (size_t)k * BB + b0;
#pragma unroll
        for (int i = 0; i < 4; ++i) acc[i] = fmaf(hr[i], w, acc[i]);
    }
    float bv = bih[n] + bhh[n];
#pragma unroll
    for (int i = 0; i < 4; ++i) gates[(size_t)(b0 + i) * 2048 + n] = acc[i] + bv;
}

// LSTM elementwise + masked state update; always store h_new (transposed)
__global__ __launch_bounds__(512) void k_lstm(const float* __restrict__ gates, const int* __restrict__ tlen,
                                              int t, float* __restrict__ hT, float* __restrict__ cT,
                                              float* __restrict__ hnT) {
    int b = blockIdx.x;
    int d = threadIdx.x;
    const float* g = gates + (size_t)b * 2048;
    float iv = g[d], fv = g[DD + d], gv = g[2 * DD + d], ov = g[3 * DD + d];
    float cv = cT[(size_t)d * BB + b];
    float si = 1.f / (1.f + expf(-iv));
    float sf = 1.f / (1.f + expf(-fv));
    float so = 1.f / (1.f + expf(-ov));
    float cn = sf * cv + si * tanhf(gv);
    float hn = so * tanhf(cn);
    hnT[(size_t)d * BB + b] = hn;
    if (t < tlen[b]) {
        hT[(size_t)d * BB + b] = hn;
        cT[(size_t)d * BB + b] = cn;
    }
}

// pred = mask ? h_new @ W_head + b_head : 0 ; one thread per v-column, 64 batch accumulators
__global__ __launch_bounds__(256) void k_head(const float* __restrict__ hnT, const float* __restrict__ W,
                                              const float* __restrict__ bias, const int* __restrict__ tlen,
                                              int t, float* __restrict__ out_pred) {
    int v = blockIdx.x * 256 + threadIdx.x;
    bool valid = v < VV;
    float acc[BB];
#pragma unroll
    for (int b = 0; b < BB; ++b) acc[b] = 0.f;
    for (int k = 0; k < DD; ++k) {
        float w = valid ? W[(size_t)k * VV + v] : 0.f;
        const float* hr = hnT + (size_t)k * BB;
#pragma unroll
        for (int b = 0; b < BB; ++b) acc[b] = fmaf(hr[b], w, acc[b]);
    }
    if (!valid) return;
    float bv = bias[v];
#pragma unroll
    for (int b = 0; b < BB; ++b) {
        bool act = t < tlen[b];
        out_pred[(size_t)b * TT * VV + (size_t)t * VV + v] = act ? (acc[b] + bv) : 0.f;
    }
}

extern "C" void kernel_launch(void* const* d_in, const int* in_sizes, int n_in,
                              void* d_out, int out_size, void* d_ws, size_t ws_size,
                              hipStream_t stream) {
    const float* enc     = (const float*)d_in[0];
    const int*   text    = (const int*)d_in[1];
    const int*   lens    = (const int*)d_in[2];
    const float* W_init_h = (const float*)d_in[3];
    const float* b_init_h = (const float*)d_in[4];
    const float* W_init_c = (const float*)d_in[5];
    const float* b_init_c = (const float*)d_in[6];
    const float* W_en    = (const float*)d_in[7];
    const float* b_en    = (const float*)d_in[8];
    const float* W_de    = (const float*)d_in[9];
    const float* b_de    = (const float*)d_in[10];
    const float* W_at    = (const float*)d_in[11];
    const float* b_at    = (const float*)d_in[12];
    const float* W_gate  = (const float*)d_in[13];
    const float* b_gate  = (const float*)d_in[14];
    const float* W_ih    = (const float*)d_in[15];
    const float* b_ih    = (const float*)d_in[16];
    const float* W_hh    = (const float*)d_in[17];
    const float* b_hh    = (const float*)d_in[18];
    const float* embed   = (const float*)d_in[19];
    const float* W_head  = (const float*)d_in[20];
    const float* b_head  = (const float*)d_in[21];

    float* outf = (float*)d_out;
    float* out_pred = outf;                               // B*T*V
    float* out_text = outf + (size_t)BB * TT * VV;        // B*L
    float* out_tlen = out_text + BB * LL;                 // B
    float* out_attn = out_tlen + BB;                      // B*T*P
    float* out_idx  = out_attn + (size_t)BB * TT * PP;    // B

    int* iws  = (int*)d_ws;
    int* idx  = iws;            // 64
    int* tlen = iws + 64;       // 64
    int* ts   = iws + 128;      // 64*32
    float* fws = (float*)d_ws + 4096;
    float* mean  = fws;  fws += (size_t)BB * CC;
    float* hT    = fws;  fws += (size_t)DD * BB;
    float* cT    = fws;  fws += (size_t)DD * BB;
    float* hnT   = fws;  fws += (size_t)DD * BB;
    float* en    = fws;  fws += (size_t)BB * PP * AA;
    float* de    = fws;  fws += (size_t)BB * AA;
    float* alpha = fws;  fws += (size_t)BB * PP;
    float* ctx   = fws;  fws += (size_t)BB * CC;
    float* xT    = fws;  fws += (size_t)(CC + EE) * BB;
    float* gates = fws;  fws += (size_t)BB * 2048;

    k_mean<<<dim3(BB, CC / 256), 256, 0, stream>>>(enc, mean);
    k_sort<<<1, 64, 0, stream>>>(text, lens, idx, tlen, ts, out_text, out_tlen, out_idx);
    k_init<<<dim3(BB, DD / 256), 256, 0, stream>>>(mean, W_init_h, b_init_h, W_init_c, b_init_c, hT, cT);
    k_enattn<<<dim3(BB * 14, 2), 256, 0, stream>>>(enc, idx, W_en, b_en, en);

    for (int t = 0; t < TT; ++t) {
        k_de<<<BB / 8, 512, 0, stream>>>(hT, W_de, b_de, de);
        k_score<<<BB, 256, 0, stream>>>(en, de, W_at, b_at, tlen, t, alpha, out_attn);
        k_ctx<<<dim3(BB, CC / 256), 256, 0, stream>>>(enc, idx, alpha, ctx);
        k_gatex<<<dim3(BB / 8, CC / 256), 256, 0, stream>>>(hT, W_gate, b_gate, ctx, xT);
        k_emb<<<(BB * EE) / 256, 256, 0, stream>>>(embed, ts, t, xT);
        k_gates<<<dim3(BB / 4, 2048 / 256), 256, 0, stream>>>(xT, W_ih, b_ih, hT, W_hh, b_hh, gates);
        k_lstm<<<BB, 512, 0, stream>>>(gates, tlen, t, hT, cT, hnT);
        k_head<<<(VV + 255) / 256, 256, 0, stream>>>(hnT, W_head, b_head, tlen, t, out_pred);
    }
}

// Round 3
// 4843.703 us; speedup vs baseline: 4.0169x; 4.0169x over previous
//
#include <hip/hip_runtime.h>
#include <hip/hip_bf16.h>
#include <math.h>

#define BB 64
#define PP 196
#define CC 2048
#define DD 512
#define AA 512
#define EE 512
#define VV 30000
#define VPAD 30016
#define LL 32
#define TT 31
#define XK 3072   // [ctx*gate (2048), emb (512), h (512)]

typedef short bf16x8 __attribute__((ext_vector_type(8)));
typedef float f32x4 __attribute__((ext_vector_type(4)));

__device__ inline unsigned short f2bf(float x) {
    __hip_bfloat16 h = __float2bfloat16(x);
    return __builtin_bit_cast(unsigned short, h);
}

// ---------- setup kernels ----------

__global__ __launch_bounds__(256) void k_mean(const float* __restrict__ enc, float* __restrict__ mean) {
    int b = blockIdx.x;
    int c = blockIdx.y * 256 + threadIdx.x;
    const float* base = enc + (size_t)b * PP * CC + c;
    float s = 0.f;
    for (int p = 0; p < PP; ++p) s += base[(size_t)p * CC];
    mean[(size_t)b * CC + c] = s * (1.0f / PP);
}

__global__ void k_sort(const int* __restrict__ text, const int* __restrict__ lens,
                       int* __restrict__ idx, int* __restrict__ tlen, int* __restrict__ ts,
                       float* __restrict__ out_text, float* __restrict__ out_tlen,
                       float* __restrict__ out_idx) {
    int j = threadIdx.x;
    __shared__ int key[BB];
    __shared__ int sidx[BB];
    key[j] = lens[j];
    __syncthreads();
    int kj = key[j];
    int pos = 0;
    for (int q = 0; q < BB; ++q) {
        int kq = key[q];
        if (kq > kj || (kq == kj && q < j)) pos++;
    }
    sidx[pos] = j;
    __syncthreads();
    int src = sidx[j];
    idx[j] = src;
    int tl = key[src] - 1;
    tlen[j] = tl;
    out_idx[j] = (float)src;
    out_tlen[j] = (float)tl;
    for (int l = 0; l < LL; ++l) {
        int tok = text[src * LL + l];
        ts[j * LL + l] = tok;
        out_text[j * LL + l] = (float)tok;
    }
}

// h0 -> xh_bf h-region (bf16), c0 -> c_f32
__global__ __launch_bounds__(256) void k_init(const float* __restrict__ mean,
                                              const float* __restrict__ Wh, const float* __restrict__ bh,
                                              const float* __restrict__ Wc, const float* __restrict__ bc,
                                              unsigned short* __restrict__ xh_bf, float* __restrict__ c_f32) {
    int b = blockIdx.x;
    int d = blockIdx.y * 256 + threadIdx.x;
    const float* m = mean + (size_t)b * CC;
    float ah = 0.f, ac = 0.f;
    for (int k = 0; k < CC; ++k) {
        float mv = m[k];
        ah = fmaf(mv, Wh[(size_t)k * DD + d], ah);
        ac = fmaf(mv, Wc[(size_t)k * DD + d], ac);
    }
    xh_bf[(size_t)b * XK + 2560 + d] = f2bf(ah + bh[d]);
    c_f32[(size_t)b * DD + d] = ac + bc[d];
}

// transpose+convert: dst[n][k] = bf16(src[k][n]); n >= N (pad) -> 0
// grid (Npad/32, K/32), block (32,8)
__global__ __launch_bounds__(256) void k_transcvt(const float* __restrict__ src, int K, int N,
                                                  unsigned short* __restrict__ dst, int dstStride, int Npad) {
    __shared__ float t[32][33];
    int n0 = blockIdx.x * 32, k0 = blockIdx.y * 32;
    int tx = threadIdx.x, ty = threadIdx.y;
#pragma unroll
    for (int r = 0; r < 4; ++r) {
        int k = k0 + ty + r * 8;
        int n = n0 + tx;
        t[ty + r * 8][tx] = (n < N) ? src[(size_t)k * N + n] : 0.f;
    }
    __syncthreads();
#pragma unroll
    for (int r = 0; r < 4; ++r) {
        int n = n0 + ty + r * 8;
        int k = k0 + tx;
        if (n < Npad) dst[(size_t)n * dstStride + k] = f2bf(t[tx][ty + r * 8]);
    }
}

// ---------- MFMA GEMM core: D[64][64-tile] = A[64][K] @ Wt[N][K]^T ----------
// block = 256 (4 waves); wave w owns cols n0+16w..+15; acc[mt] covers m = mt*16..mt*16+15
template<int K, int LDA>
__device__ inline void gemm64(const unsigned short* __restrict__ A,
                              const unsigned short* __restrict__ Wt, int ldb, int n0,
                              f32x4 acc[4]) {
    int lane = threadIdx.x & 63;
    int w = threadIdx.x >> 6;
    const unsigned short* a0 = A + (size_t)(lane & 15) * LDA + ((lane >> 4) * 8);
    const unsigned short* b0 = Wt + (size_t)(n0 + w * 16 + (lane & 15)) * ldb + ((lane >> 4) * 8);
#pragma unroll
    for (int mt = 0; mt < 4; ++mt) acc[mt] = (f32x4){0.f, 0.f, 0.f, 0.f};
    for (int kc = 0; kc < K / 32; ++kc) {
        bf16x8 bfr = *reinterpret_cast<const bf16x8*>(b0 + kc * 32);
#pragma unroll
        for (int mt = 0; mt < 4; ++mt) {
            bf16x8 afr = *reinterpret_cast<const bf16x8*>(a0 + (size_t)mt * 16 * LDA + kc * 32);
            acc[mt] = __builtin_amdgcn_mfma_f32_16x16x32_bf16(afr, bfr, acc[mt], 0, 0, 0);
        }
    }
}

// de = h @ W_de + b_de ; grid 8
__global__ __launch_bounds__(256) void k_de_mfma(const unsigned short* __restrict__ xh_bf,
                                                 const unsigned short* __restrict__ Wt,
                                                 const float* __restrict__ bias, float* __restrict__ de) {
    int n0 = blockIdx.x * 64;
    f32x4 acc[4];
    gemm64<DD, XK>(xh_bf + 2560, Wt, DD, n0, acc);
    int lane = threadIdx.x & 63, w = threadIdx.x >> 6;
    int n = n0 + w * 16 + (lane & 15);
    float bv = bias[n];
#pragma unroll
    for (int mt = 0; mt < 4; ++mt)
#pragma unroll
        for (int r = 0; r < 4; ++r) {
            int m = mt * 16 + (lane >> 4) * 4 + r;
            de[(size_t)m * AA + n] = acc[mt][r] + bv;
        }
}

// gate = sigmoid(h @ W_gate + b); xh[ctx region] = bf16(ctx * gate) ; grid 32
__global__ __launch_bounds__(256) void k_gatex_mfma(unsigned short* __restrict__ xh_bf,
                                                    const unsigned short* __restrict__ Wt,
                                                    const float* __restrict__ bias,
                                                    const float* __restrict__ ctx) {
    int n0 = blockIdx.x * 64;
    f32x4 acc[4];
    gemm64<DD, XK>(xh_bf + 2560, Wt, DD, n0, acc);
    int lane = threadIdx.x & 63, w = threadIdx.x >> 6;
    int n = n0 + w * 16 + (lane & 15);
    float bv = bias[n];
#pragma unroll
    for (int mt = 0; mt < 4; ++mt)
#pragma unroll
        for (int r = 0; r < 4; ++r) {
            int m = mt * 16 + (lane >> 4) * 4 + r;
            float g = 1.f / (1.f + expf(-(acc[mt][r] + bv)));
            xh_bf[(size_t)m * XK + n] = f2bf(ctx[(size_t)m * CC + n] * g);
        }
}

// gates = xh @ [W_ih; W_hh] + b_ih + b_hh ; grid 32
__global__ __launch_bounds__(256) void k_gates_mfma(const unsigned short* __restrict__ xh_bf,
                                                    const unsigned short* __restrict__ Wt,
                                                    const float* __restrict__ bih,
                                                    const float* __restrict__ bhh,
                                                    float* __restrict__ gates) {
    int n0 = blockIdx.x * 64;
    f32x4 acc[4];
    gemm64<XK, XK>(xh_bf, Wt, XK, n0, acc);
    int lane = threadIdx.x & 63, w = threadIdx.x >> 6;
    int n = n0 + w * 16 + (lane & 15);
    float bv = bih[n] + bhh[n];
#pragma unroll
    for (int mt = 0; mt < 4; ++mt)
#pragma unroll
        for (int r = 0; r < 4; ++r) {
            int m = mt * 16 + (lane >> 4) * 4 + r;
            gates[(size_t)m * 2048 + n] = acc[mt][r] + bv;
        }
}

// pred = mask ? hn @ W_head + b_head : 0 ; grid 469 (VPAD/64)
__global__ __launch_bounds__(256) void k_head_mfma(const unsigned short* __restrict__ hn_bf,
                                                   const unsigned short* __restrict__ Wt,
                                                   const float* __restrict__ bias,
                                                   const int* __restrict__ tlen, int t,
                                                   float* __restrict__ out_pred) {
    int n0 = blockIdx.x * 64;
    f32x4 acc[4];
    gemm64<DD, DD>(hn_bf, Wt, DD, n0, acc);
    int lane = threadIdx.x & 63, w = threadIdx.x >> 6;
    int v = n0 + w * 16 + (lane & 15);
    if (v >= VV) return;
    float bv = bias[v];
#pragma unroll
    for (int mt = 0; mt < 4; ++mt)
#pragma unroll
        for (int r = 0; r < 4; ++r) {
            int b = mt * 16 + (lane >> 4) * 4 + r;
            bool act = t < tlen[b];
            out_pred[(size_t)b * TT * VV + (size_t)t * VV + v] = act ? (acc[mt][r] + bv) : 0.f;
        }
}

// en = img_s @ W_en + b_en : M=12544=196*64 tiles, N=512 per block; grid 196
__global__ __launch_bounds__(256) void k_enattn_mfma(const float* __restrict__ enc,
                                                     const int* __restrict__ idx,
                                                     const unsigned short* __restrict__ Wt,
                                                     const float* __restrict__ bias,
                                                     float* __restrict__ en) {
    int m0 = blockIdx.x * 64;
    int lane = threadIdx.x & 63, w = threadIdx.x >> 6;
    // A row pointers per m-tile (on-the-fly f32->bf16)
    const float* aptr[4];
#pragma unroll
    for (int mt = 0; mt < 4; ++mt) {
        int row = m0 + mt * 16 + (lane & 15);
        int b = row / PP;
        int p = row - b * PP;
        aptr[mt] = enc + ((size_t)idx[b] * PP + p) * CC + ((lane >> 4) * 8);
    }
    const unsigned short* bptr[8];
#pragma unroll
    for (int nt = 0; nt < 8; ++nt) {
        int rowB = nt * 64 + w * 16 + (lane & 15);
        bptr[nt] = Wt + (size_t)rowB * CC + ((lane >> 4) * 8);
    }
    f32x4 acc[4][8];
#pragma unroll
    for (int mt = 0; mt < 4; ++mt)
#pragma unroll
        for (int nt = 0; nt < 8; ++nt) acc[mt][nt] = (f32x4){0.f, 0.f, 0.f, 0.f};

    for (int kc = 0; kc < CC / 32; ++kc) {
        bf16x8 afr[4];
#pragma unroll
        for (int mt = 0; mt < 4; ++mt) {
            f32x4 lo = *reinterpret_cast<const f32x4*>(aptr[mt] + kc * 32);
            f32x4 hi = *reinterpret_cast<const f32x4*>(aptr[mt] + kc * 32 + 4);
            bf16x8 a;
            a[0] = (short)f2bf(lo[0]); a[1] = (short)f2bf(lo[1]);
            a[2] = (short)f2bf(lo[2]); a[3] = (short)f2bf(lo[3]);
            a[4] = (short)f2bf(hi[0]); a[5] = (short)f2bf(hi[1]);
            a[6] = (short)f2bf(hi[2]); a[7] = (short)f2bf(hi[3]);
            afr[mt] = a;
        }
#pragma unroll
        for (int nt = 0; nt < 8; ++nt) {
            bf16x8 bfr = *reinterpret_cast<const bf16x8*>(bptr[nt] + kc * 32);
#pragma unroll
            for (int mt = 0; mt < 4; ++mt)
                acc[mt][nt] = __builtin_amdgcn_mfma_f32_16x16x32_bf16(afr[mt], bfr, acc[mt][nt], 0, 0, 0);
        }
    }
#pragma unroll
    for (int nt = 0; nt < 8; ++nt) {
        int n = nt * 64 + w * 16 + (lane & 15);
        float bv = bias[n];
#pragma unroll
        for (int mt = 0; mt < 4; ++mt)
#pragma unroll
            for (int r = 0; r < 4; ++r) {
                int m = m0 + mt * 16 + (lane >> 4) * 4 + r;
                en[(size_t)m * AA + n] = acc[mt][nt][r] + bv;
            }
    }
}

// ---------- per-step VALU kernels ----------

__global__ __launch_bounds__(256) void k_score(const float* __restrict__ en, const float* __restrict__ de,
                                               const float* __restrict__ Wat, const float* __restrict__ bat,
                                               const int* __restrict__ tlen, int t,
                                               float* __restrict__ alpha, float* __restrict__ out_attn) {
    int b = blockIdx.x;
    int tid = threadIdx.x;
    __shared__ float deL[AA];
    __shared__ float watL[AA];
    __shared__ float red[256];
    deL[tid] = de[(size_t)b * AA + tid];
    deL[tid + 256] = de[(size_t)b * AA + 256 + tid];
    watL[tid] = Wat[tid];
    watL[tid + 256] = Wat[tid + 256];
    __syncthreads();
    float s = 0.f;
    if (tid < PP) {
        const float4* er4 = (const float4*)(en + ((size_t)b * PP + tid) * AA);
        for (int a4 = 0; a4 < AA / 4; ++a4) {
            float4 v = er4[a4];
            float v0 = fmaxf(v.x + deL[4 * a4 + 0], 0.f);
            float v1 = fmaxf(v.y + deL[4 * a4 + 1], 0.f);
            float v2 = fmaxf(v.z + deL[4 * a4 + 2], 0.f);
            float v3 = fmaxf(v.w + deL[4 * a4 + 3], 0.f);
            s = fmaf(v0, watL[4 * a4 + 0], s);
            s = fmaf(v1, watL[4 * a4 + 1], s);
            s = fmaf(v2, watL[4 * a4 + 2], s);
            s = fmaf(v3, watL[4 * a4 + 3], s);
        }
        s += bat[0];
    }
    red[tid] = (tid < PP) ? s : -3.4e38f;
    __syncthreads();
    for (int st = 128; st > 0; st >>= 1) {
        if (tid < st) red[tid] = fmaxf(red[tid], red[tid + st]);
        __syncthreads();
    }
    float m = red[0];
    __syncthreads();
    float e = (tid < PP) ? expf(s - m) : 0.f;
    red[tid] = e;
    __syncthreads();
    for (int st = 128; st > 0; st >>= 1) {
        if (tid < st) red[tid] += red[tid + st];
        __syncthreads();
    }
    float inv = 1.0f / red[0];
    if (tid < PP) {
        float al = e * inv;
        alpha[(size_t)b * PP + tid] = al;
        bool act = t < tlen[b];
        out_attn[((size_t)b * TT + t) * PP + tid] = act ? al : 0.f;
    }
}

// ctx[b,c] = sum_p alpha[b,p]*img[p,c]; one block per b, thread handles 8 c
__global__ __launch_bounds__(256) void k_ctx(const float* __restrict__ enc, const int* __restrict__ idx,
                                             const float* __restrict__ alpha, float* __restrict__ ctx) {
    int b = blockIdx.x;
    int c0 = threadIdx.x * 8;
    const float* img = enc + (size_t)idx[b] * PP * CC + c0;
    __shared__ float al[PP];
    if (threadIdx.x < PP) al[threadIdx.x] = alpha[(size_t)b * PP + threadIdx.x];
    __syncthreads();
    f32x4 s0 = {0.f, 0.f, 0.f, 0.f}, s1 = {0.f, 0.f, 0.f, 0.f};
    for (int p = 0; p < PP; ++p) {
        float a = al[p];
        f32x4 lo = *reinterpret_cast<const f32x4*>(img + (size_t)p * CC);
        f32x4 hi = *reinterpret_cast<const f32x4*>(img + (size_t)p * CC + 4);
#pragma unroll
        for (int j = 0; j < 4; ++j) { s0[j] = fmaf(a, lo[j], s0[j]); s1[j] = fmaf(a, hi[j], s1[j]); }
    }
    float* dst = ctx + (size_t)b * CC + c0;
#pragma unroll
    for (int j = 0; j < 4; ++j) { dst[j] = s0[j]; dst[4 + j] = s1[j]; }
}

// xh[emb region] = bf16(embed[tok])
__global__ __launch_bounds__(256) void k_emb(const float* __restrict__ embed, const int* __restrict__ ts,
                                             int t, unsigned short* __restrict__ xh_bf) {
    int gid = blockIdx.x * 256 + threadIdx.x;  // 64*512
    int e = gid & 511;
    int b = gid >> 9;
    int tok = ts[b * LL + t];
    xh_bf[(size_t)b * XK + CC + e] = f2bf(embed[(size_t)tok * EE + e]);
}

// LSTM pointwise: update c (f32), xh h-region (masked), hn_bf (always)
__global__ __launch_bounds__(512) void k_lstm(const float* __restrict__ gates, const int* __restrict__ tlen,
                                              int t, unsigned short* __restrict__ xh_bf,
                                              float* __restrict__ c_f32, unsigned short* __restrict__ hn_bf) {
    int b = blockIdx.x;
    int d = threadIdx.x;
    const float* g = gates + (size_t)b * 2048;
    float iv = g[d], fv = g[DD + d], gv = g[2 * DD + d], ov = g[3 * DD + d];
    float cv = c_f32[(size_t)b * DD + d];
    float si = 1.f / (1.f + expf(-iv));
    float sf = 1.f / (1.f + expf(-fv));
    float so = 1.f / (1.f + expf(-ov));
    float cn = sf * cv + si * tanhf(gv);
    float hn = so * tanhf(cn);
    hn_bf[(size_t)b * DD + d] = f2bf(hn);
    if (t < tlen[b]) {
        xh_bf[(size_t)b * XK + 2560 + d] = f2bf(hn);
        c_f32[(size_t)b * DD + d] = cn;
    }
}

extern "C" void kernel_launch(void* const* d_in, const int* in_sizes, int n_in,
                              void* d_out, int out_size, void* d_ws, size_t ws_size,
                              hipStream_t stream) {
    const float* enc     = (const float*)d_in[0];
    const int*   text    = (const int*)d_in[1];
    const int*   lens    = (const int*)d_in[2];
    const float* W_init_h = (const float*)d_in[3];
    const float* b_init_h = (const float*)d_in[4];
    const float* W_init_c = (const float*)d_in[5];
    const float* b_init_c = (const float*)d_in[6];
    const float* W_en    = (const float*)d_in[7];
    const float* b_en    = (const float*)d_in[8];
    const float* W_de    = (const float*)d_in[9];
    const float* b_de    = (const float*)d_in[10];
    const float* W_at    = (const float*)d_in[11];
    const float* b_at    = (const float*)d_in[12];
    const float* W_gate  = (const float*)d_in[13];
    const float* b_gate  = (const float*)d_in[14];
    const float* W_ih    = (const float*)d_in[15];
    const float* b_ih    = (const float*)d_in[16];
    const float* W_hh    = (const float*)d_in[17];
    const float* b_hh    = (const float*)d_in[18];
    const float* embed   = (const float*)d_in[19];
    const float* W_head  = (const float*)d_in[20];
    const float* b_head  = (const float*)d_in[21];

    float* outf = (float*)d_out;
    float* out_pred = outf;                               // B*T*V
    float* out_text = outf + (size_t)BB * TT * VV;        // B*L
    float* out_tlen = out_text + BB * LL;                 // B
    float* out_attn = out_tlen + BB;                      // B*T*P
    float* out_idx  = out_attn + (size_t)BB * TT * PP;    // B

    // ---- workspace layout ----
    char* wsb = (char*)d_ws;
    int* idx  = (int*)wsb;              // 64
    int* tlen = idx + 64;               // 64
    int* ts   = tlen + 64;              // 64*32
    float* fw = (float*)(wsb + 16384);
    float* mean  = fw;  fw += (size_t)BB * CC;      // 131072
    float* c_f32 = fw;  fw += (size_t)BB * DD;      // 32768
    float* en    = fw;  fw += (size_t)BB * PP * AA; // 6422528
    float* de    = fw;  fw += (size_t)BB * AA;      // 32768
    float* alpha = fw;  fw += (size_t)BB * PP;      // 12544
    float* ctx   = fw;  fw += (size_t)BB * CC;      // 131072
    float* gates = fw;  fw += (size_t)BB * 2048;    // 131072
    unsigned short* us = (unsigned short*)fw;
    unsigned short* xh_bf   = us;  us += (size_t)BB * XK;    // h/ctx/emb activations
    unsigned short* hn_bf   = us;  us += (size_t)BB * DD;
    unsigned short* Wt_en   = us;  us += (size_t)AA * CC;    // [512][2048]
    unsigned short* Wt_de   = us;  us += (size_t)AA * DD;    // [512][512]
    unsigned short* Wt_gate = us;  us += (size_t)CC * DD;    // [2048][512]
    unsigned short* Wt_ihh  = us;  us += (size_t)2048 * XK;  // [2048][3072]
    unsigned short* Wt_head = us;  us += (size_t)VPAD * DD;  // [30016][512]

    // ---- setup ----
    k_mean<<<dim3(BB, CC / 256), 256, 0, stream>>>(enc, mean);
    k_sort<<<1, 64, 0, stream>>>(text, lens, idx, tlen, ts, out_text, out_tlen, out_idx);
    k_init<<<dim3(BB, DD / 256), 256, 0, stream>>>(mean, W_init_h, b_init_h, W_init_c, b_init_c, xh_bf, c_f32);

    dim3 tb(32, 8);
    k_transcvt<<<dim3(AA / 32, CC / 32), tb, 0, stream>>>(W_en, CC, AA, Wt_en, CC, AA);
    k_transcvt<<<dim3(AA / 32, DD / 32), tb, 0, stream>>>(W_de, DD, AA, Wt_de, DD, AA);
    k_transcvt<<<dim3(CC / 32, DD / 32), tb, 0, stream>>>(W_gate, DD, CC, Wt_gate, DD, CC);
    k_transcvt<<<dim3(2048 / 32, 2560 / 32), tb, 0, stream>>>(W_ih, 2560, 2048, Wt_ihh, XK, 2048);
    k_transcvt<<<dim3(2048 / 32, DD / 32), tb, 0, stream>>>(W_hh, DD, 2048, Wt_ihh + 2560, XK, 2048);
    k_transcvt<<<dim3(VPAD / 32, DD / 32), tb, 0, stream>>>(W_head, DD, VV, Wt_head, DD, VPAD);

    k_enattn_mfma<<<PP, 256, 0, stream>>>(enc, idx, Wt_en, b_en, en);

    // ---- decode loop ----
    for (int t = 0; t < TT; ++t) {
        k_de_mfma<<<AA / 64, 256, 0, stream>>>(xh_bf, Wt_de, b_de, de);
        k_score<<<BB, 256, 0, stream>>>(en, de, W_at, b_at, tlen, t, alpha, out_attn);
        k_ctx<<<BB, 256, 0, stream>>>(enc, idx, alpha, ctx);
        k_gatex_mfma<<<CC / 64, 256, 0, stream>>>(xh_bf, Wt_gate, b_gate, ctx);
        k_emb<<<(BB * EE) / 256, 256, 0, stream>>>(embed, ts, t, xh_bf);
        k_gates_mfma<<<2048 / 64, 256, 0, stream>>>(xh_bf, Wt_ihh, b_ih, b_hh, gates);
        k_lstm<<<BB, 512, 0, stream>>>(gates, tlen, t, xh_bf, c_f32, hn_bf);
        k_head_mfma<<<VPAD / 64, 256, 0, stream>>>(hn_bf, Wt_head, b_head, tlen, t, out_pred);
    }
}

// Round 4
// 4087.864 us; speedup vs baseline: 4.7596x; 1.1849x over previous
//
#include <hip/hip_runtime.h>
#include <hip/hip_bf16.h>
#include <math.h>

#define BB 64
#define PP 196
#define CC 2048
#define DD 512
#define AA 512
#define EE 512
#define VV 30000
#define VPAD 30016
#define LL 32
#define TT 31
#define XH 2560   // [ctx*gate (2048) | h (512)]

typedef short bf16x8 __attribute__((ext_vector_type(8)));
typedef float f32x4 __attribute__((ext_vector_type(4)));

__device__ inline unsigned short f2bf(float x) {
    __hip_bfloat16 h = __float2bfloat16(x);
    return __builtin_bit_cast(unsigned short, h);
}
__device__ inline float bf2f(unsigned short u) {
    unsigned int x = ((unsigned int)u) << 16;
    return __builtin_bit_cast(float, x);
}

// MFMA core: acc[mt] (mt=0..3 m-tiles of 16 rows) over K; a0/b0 pre-offset per lane.
template<int K, int LDA>
__device__ inline void mm4(const unsigned short* __restrict__ a0,
                           const unsigned short* __restrict__ b0,
                           int ldb, f32x4 acc[4]) {
#pragma unroll
    for (int kc = 0; kc < K / 32; ++kc) {
        bf16x8 bfr = *reinterpret_cast<const bf16x8*>(b0 + kc * 32);
#pragma unroll
        for (int mt = 0; mt < 4; ++mt) {
            bf16x8 afr = *reinterpret_cast<const bf16x8*>(a0 + (size_t)mt * 16 * LDA + kc * 32);
            acc[mt] = __builtin_amdgcn_mfma_f32_16x16x32_bf16(afr, bfr, acc[mt], 0, 0, 0);
        }
    }
}

// ---------- setup kernels ----------

__global__ __launch_bounds__(256) void k_mean(const float* __restrict__ enc, float* __restrict__ mean) {
    int b = blockIdx.x;
    int c = blockIdx.y * 256 + threadIdx.x;
    const float* base = enc + (size_t)b * PP * CC + c;
    float s = 0.f;
    for (int p = 0; p < PP; ++p) s += base[(size_t)p * CC];
    mean[(size_t)b * CC + c] = s * (1.0f / PP);
}

__global__ void k_sort(const int* __restrict__ text, const int* __restrict__ lens,
                       int* __restrict__ idx, int* __restrict__ tlen, int* __restrict__ ts,
                       float* __restrict__ out_text, float* __restrict__ out_tlen,
                       float* __restrict__ out_idx) {
    int j = threadIdx.x;
    __shared__ int key[BB];
    __shared__ int sidx[BB];
    key[j] = lens[j];
    __syncthreads();
    int kj = key[j];
    int pos = 0;
    for (int q = 0; q < BB; ++q) {
        int kq = key[q];
        if (kq > kj || (kq == kj && q < j)) pos++;
    }
    sidx[pos] = j;
    __syncthreads();
    int src = sidx[j];
    idx[j] = src;
    int tl = key[src] - 1;
    tlen[j] = tl;
    out_idx[j] = (float)src;
    out_tlen[j] = (float)tl;
    for (int l = 0; l < LL; ++l) {
        int tok = text[src * LL + l];
        ts[j * LL + l] = tok;
        out_text[j * LL + l] = (float)tok;
    }
}

__global__ __launch_bounds__(256) void k_init(const float* __restrict__ mean,
                                              const float* __restrict__ Wh, const float* __restrict__ bh,
                                              const float* __restrict__ Wc, const float* __restrict__ bc,
                                              unsigned short* __restrict__ xh_bf, float* __restrict__ c_f32) {
    int b = blockIdx.x;
    int d = blockIdx.y * 256 + threadIdx.x;
    const float* m = mean + (size_t)b * CC;
    float ah = 0.f, ac = 0.f;
    for (int k = 0; k < CC; ++k) {
        float mv = m[k];
        ah = fmaf(mv, Wh[(size_t)k * DD + d], ah);
        ac = fmaf(mv, Wc[(size_t)k * DD + d], ac);
    }
    xh_bf[(size_t)b * XH + CC + d] = f2bf(ah + bh[d]);
    c_f32[(size_t)b * DD + d] = ac + bc[d];
}

// sorted gather + f32->bf16: enc_bf[bs*196+p][c] = bf16(enc[idx[bs]][p][c]); grid 12544
__global__ __launch_bounds__(256) void k_cvtenc(const float* __restrict__ enc, const int* __restrict__ idx,
                                                unsigned short* __restrict__ enc_bf) {
    int row = blockIdx.x;           // bs*196+p
    int bs = row / PP, p = row - bs * PP;
    int c0 = threadIdx.x * 8;
    const float* src = enc + ((size_t)idx[bs] * PP + p) * CC + c0;
    f32x4 lo = *reinterpret_cast<const f32x4*>(src);
    f32x4 hi = *reinterpret_cast<const f32x4*>(src + 4);
    unsigned short* dst = enc_bf + (size_t)row * CC + c0;
    bf16x8 v;
    v[0] = (short)f2bf(lo[0]); v[1] = (short)f2bf(lo[1]);
    v[2] = (short)f2bf(lo[2]); v[3] = (short)f2bf(lo[3]);
    v[4] = (short)f2bf(hi[0]); v[5] = (short)f2bf(hi[1]);
    v[6] = (short)f2bf(hi[2]); v[7] = (short)f2bf(hi[3]);
    *reinterpret_cast<bf16x8*>(dst) = v;
}

// transpose+convert: dst[n][k] = bf16(src[k][n]); n >= N -> 0 ; grid (Npad/32, K/32), block (32,8)
__global__ __launch_bounds__(256) void k_transcvt(const float* __restrict__ src, int K, int N,
                                                  unsigned short* __restrict__ dst, int dstStride, int Npad) {
    __shared__ float t[32][33];
    int n0 = blockIdx.x * 32, k0 = blockIdx.y * 32;
    int tx = threadIdx.x, ty = threadIdx.y;
#pragma unroll
    for (int r = 0; r < 4; ++r) {
        int k = k0 + ty + r * 8;
        int n = n0 + tx;
        t[ty + r * 8][tx] = (n < N) ? src[(size_t)k * N + n] : 0.f;
    }
    __syncthreads();
#pragma unroll
    for (int r = 0; r < 4; ++r) {
        int n = n0 + ty + r * 8;
        int k = k0 + tx;
        if (n < Npad) dst[(size_t)n * dstStride + k] = f2bf(t[tx][ty + r * 8]);
    }
}

// emb_all[(t*64+b)][e] = bf16(embed[ts[b][t]][e]) ; grid TT*BB
__global__ __launch_bounds__(256) void k_emball(const float* __restrict__ embed, const int* __restrict__ ts,
                                                unsigned short* __restrict__ emb_all) {
    int row = blockIdx.x;           // t*64+b
    int t = row >> 6, b = row & 63;
    int tok = ts[b * LL + t];
    int e = threadIdx.x * 2;
    const float* src = embed + (size_t)tok * EE + e;
    unsigned short* dst = emb_all + (size_t)row * EE + e;
    dst[0] = f2bf(src[0]);
    dst[1] = f2bf(src[1]);
}

// embW[t][m][n] = emb_all[t*64+m] @ Wt_emb[n] + b_ih[n] + b_hh[n] ; grid (TT, 2048/64), 4 waves
__global__ __launch_bounds__(256) void k_embw(const unsigned short* __restrict__ emb_all,
                                              const unsigned short* __restrict__ Wt_emb,
                                              const float* __restrict__ bih, const float* __restrict__ bhh,
                                              float* __restrict__ embW) {
    int tstep = blockIdx.x;
    int n0 = blockIdx.y * 64;
    int lane = threadIdx.x & 63, w = threadIdx.x >> 6;
    const unsigned short* a0 = emb_all + ((size_t)tstep * 64 + (lane & 15)) * EE + ((lane >> 4) * 8);
    const unsigned short* b0 = Wt_emb + (size_t)(n0 + w * 16 + (lane & 15)) * EE + ((lane >> 4) * 8);
    f32x4 acc[4];
#pragma unroll
    for (int mt = 0; mt < 4; ++mt) acc[mt] = (f32x4){0.f, 0.f, 0.f, 0.f};
    mm4<EE, EE>(a0, b0, EE, acc);
    int n = n0 + w * 16 + (lane & 15);
    float bv = bih[n] + bhh[n];
#pragma unroll
    for (int mt = 0; mt < 4; ++mt)
#pragma unroll
        for (int r = 0; r < 4; ++r) {
            int m = mt * 16 + (lane >> 4) * 4 + r;
            embW[((size_t)tstep * 64 + m) * 2048 + n] = acc[mt][r] + bv;
        }
}

// en = enc_bf(sorted) @ W_en + b_en ; grid 196, 4 waves, N=512 per block (8 n-tiles)
__global__ __launch_bounds__(256) void k_enattn_mfma(const unsigned short* __restrict__ enc_bf,
                                                     const unsigned short* __restrict__ Wt,
                                                     const float* __restrict__ bias,
                                                     float* __restrict__ en) {
    int m0 = blockIdx.x * 64;
    int lane = threadIdx.x & 63, w = threadIdx.x >> 6;
    const unsigned short* a0 = enc_bf + (size_t)(m0 + (lane & 15)) * CC + ((lane >> 4) * 8);
    const unsigned short* bptr[8];
#pragma unroll
    for (int nt = 0; nt < 8; ++nt) {
        int rowB = nt * 64 + w * 16 + (lane & 15);
        bptr[nt] = Wt + (size_t)rowB * CC + ((lane >> 4) * 8);
    }
    f32x4 acc[4][8];
#pragma unroll
    for (int mt = 0; mt < 4; ++mt)
#pragma unroll
        for (int nt = 0; nt < 8; ++nt) acc[mt][nt] = (f32x4){0.f, 0.f, 0.f, 0.f};

    for (int kc = 0; kc < CC / 32; ++kc) {
        bf16x8 afr[4];
#pragma unroll
        for (int mt = 0; mt < 4; ++mt)
            afr[mt] = *reinterpret_cast<const bf16x8*>(a0 + (size_t)mt * 16 * CC + kc * 32);
#pragma unroll
        for (int nt = 0; nt < 8; ++nt) {
            bf16x8 bfr = *reinterpret_cast<const bf16x8*>(bptr[nt] + kc * 32);
#pragma unroll
            for (int mt = 0; mt < 4; ++mt)
                acc[mt][nt] = __builtin_amdgcn_mfma_f32_16x16x32_bf16(afr[mt], bfr, acc[mt][nt], 0, 0, 0);
        }
    }
#pragma unroll
    for (int nt = 0; nt < 8; ++nt) {
        int n = nt * 64 + w * 16 + (lane & 15);
        float bv = bias[n];
#pragma unroll
        for (int mt = 0; mt < 4; ++mt)
#pragma unroll
            for (int r = 0; r < 4; ++r) {
                int m = m0 + mt * 16 + (lane >> 4) * 4 + r;
                en[(size_t)m * AA + n] = acc[mt][nt][r] + bv;
            }
    }
}

// ---------- per-step kernels ----------

// de = h @ W_de + b_de ; 1-wave blocks, 16 cols each, grid 32
__global__ __launch_bounds__(64) void k_de_mfma(const unsigned short* __restrict__ xh_bf,
                                                const unsigned short* __restrict__ Wt,
                                                const float* __restrict__ bias, float* __restrict__ de) {
    int n0 = blockIdx.x * 16;
    int lane = threadIdx.x;
    const unsigned short* a0 = xh_bf + CC + (size_t)(lane & 15) * XH + ((lane >> 4) * 8);
    const unsigned short* b0 = Wt + (size_t)(n0 + (lane & 15)) * DD + ((lane >> 4) * 8);
    f32x4 acc[4];
#pragma unroll
    for (int mt = 0; mt < 4; ++mt) acc[mt] = (f32x4){0.f, 0.f, 0.f, 0.f};
    mm4<DD, XH>(a0, b0, DD, acc);
    int n = n0 + (lane & 15);
    float bv = bias[n];
#pragma unroll
    for (int mt = 0; mt < 4; ++mt)
#pragma unroll
        for (int r = 0; r < 4; ++r) {
            int m = mt * 16 + (lane >> 4) * 4 + r;
            de[(size_t)m * AA + n] = acc[mt][r] + bv;
        }
}

__global__ __launch_bounds__(256) void k_score(const float* __restrict__ en, const float* __restrict__ de,
                                               const float* __restrict__ Wat, const float* __restrict__ bat,
                                               const int* __restrict__ tlen, int t,
                                               float* __restrict__ alpha, float* __restrict__ out_attn) {
    int b = blockIdx.x;
    int tid = threadIdx.x;
    __shared__ float deL[AA];
    __shared__ float watL[AA];
    __shared__ float red[256];
    deL[tid] = de[(size_t)b * AA + tid];
    deL[tid + 256] = de[(size_t)b * AA + 256 + tid];
    watL[tid] = Wat[tid];
    watL[tid + 256] = Wat[tid + 256];
    __syncthreads();
    float s = 0.f;
    if (tid < PP) {
        const float4* er4 = (const float4*)(en + ((size_t)b * PP + tid) * AA);
        for (int a4 = 0; a4 < AA / 4; ++a4) {
            float4 v = er4[a4];
            float v0 = fmaxf(v.x + deL[4 * a4 + 0], 0.f);
            float v1 = fmaxf(v.y + deL[4 * a4 + 1], 0.f);
            float v2 = fmaxf(v.z + deL[4 * a4 + 2], 0.f);
            float v3 = fmaxf(v.w + deL[4 * a4 + 3], 0.f);
            s = fmaf(v0, watL[4 * a4 + 0], s);
            s = fmaf(v1, watL[4 * a4 + 1], s);
            s = fmaf(v2, watL[4 * a4 + 2], s);
            s = fmaf(v3, watL[4 * a4 + 3], s);
        }
        s += bat[0];
    }
    red[tid] = (tid < PP) ? s : -3.4e38f;
    __syncthreads();
    for (int st = 128; st > 0; st >>= 1) {
        if (tid < st) red[tid] = fmaxf(red[tid], red[tid + st]);
        __syncthreads();
    }
    float m = red[0];
    __syncthreads();
    float e = (tid < PP) ? expf(s - m) : 0.f;
    red[tid] = e;
    __syncthreads();
    for (int st = 128; st > 0; st >>= 1) {
        if (tid < st) red[tid] += red[tid + st];
        __syncthreads();
    }
    float inv = 1.0f / red[0];
    if (tid < PP) {
        float al = e * inv;
        alpha[(size_t)b * PP + tid] = al;
        bool act = t < tlen[b];
        out_attn[((size_t)b * TT + t) * PP + tid] = act ? al : 0.f;
    }
}

// ctx[b,c] = sum_p alpha[b,p]*enc_bf[b,p,c]; one block per b, thread handles 8 c
__global__ __launch_bounds__(256) void k_ctx(const unsigned short* __restrict__ enc_bf,
                                             const float* __restrict__ alpha, float* __restrict__ ctx) {
    int b = blockIdx.x;
    int c0 = threadIdx.x * 8;
    const unsigned short* img = enc_bf + (size_t)b * PP * CC + c0;
    __shared__ float al[PP];
    if (threadIdx.x < PP) al[threadIdx.x] = alpha[(size_t)b * PP + threadIdx.x];
    __syncthreads();
    float s[8] = {0.f, 0.f, 0.f, 0.f, 0.f, 0.f, 0.f, 0.f};
    for (int p = 0; p < PP; ++p) {
        float a = al[p];
        bf16x8 v = *reinterpret_cast<const bf16x8*>(img + (size_t)p * CC);
#pragma unroll
        for (int j = 0; j < 8; ++j) s[j] = fmaf(a, bf2f((unsigned short)v[j]), s[j]);
    }
    float* dst = ctx + (size_t)b * CC + c0;
#pragma unroll
    for (int j = 0; j < 8; ++j) dst[j] = s[j];
}

// gate = sigmoid(h @ W_gate + b); xh[ctxg] = bf16(ctx * gate) ; 1-wave blocks, grid 128
__global__ __launch_bounds__(64) void k_gatex_mfma(unsigned short* __restrict__ xh_bf,
                                                   const unsigned short* __restrict__ Wt,
                                                   const float* __restrict__ bias,
                                                   const float* __restrict__ ctx) {
    int n0 = blockIdx.x * 16;
    int lane = threadIdx.x;
    const unsigned short* a0 = xh_bf + CC + (size_t)(lane & 15) * XH + ((lane >> 4) * 8);
    const unsigned short* b0 = Wt + (size_t)(n0 + (lane & 15)) * DD + ((lane >> 4) * 8);
    f32x4 acc[4];
#pragma unroll
    for (int mt = 0; mt < 4; ++mt) acc[mt] = (f32x4){0.f, 0.f, 0.f, 0.f};
    mm4<DD, XH>(a0, b0, DD, acc);
    int n = n0 + (lane & 15);
    float bv = bias[n];
#pragma unroll
    for (int mt = 0; mt < 4; ++mt)
#pragma unroll
        for (int r = 0; r < 4; ++r) {
            int m = mt * 16 + (lane >> 4) * 4 + r;
            float g = 1.f / (1.f + expf(-(acc[mt][r] + bv)));
            xh_bf[(size_t)m * XH + n] = f2bf(ctx[(size_t)m * CC + n] * g);
        }
}

// gates GEMM (acc init from embW) + fused LSTM pointwise ; 1-wave blocks, grid 32 (16 d each)
__global__ __launch_bounds__(64) void k_gateslstm(const unsigned short* __restrict__ xh_bf,
                                                  const unsigned short* __restrict__ Wt,
                                                  const float* __restrict__ embW,
                                                  const int* __restrict__ tlen, int t,
                                                  unsigned short* __restrict__ xh_out,
                                                  float* __restrict__ c_f32,
                                                  unsigned short* __restrict__ hn_bf) {
    int d0 = blockIdx.x * 16;
    int lane = threadIdx.x;
    int col = lane & 15;
    const unsigned short* a0 = xh_bf + (size_t)col * XH + ((lane >> 4) * 8);
    const unsigned short* bptr[4];
#pragma unroll
    for (int g = 0; g < 4; ++g)
        bptr[g] = Wt + (size_t)(g * DD + d0 + col) * XH + ((lane >> 4) * 8);

    f32x4 acc[4][4];  // [gate][m-tile]
    const float* ew = embW + (size_t)t * 64 * 2048;
#pragma unroll
    for (int g = 0; g < 4; ++g)
#pragma unroll
        for (int mt = 0; mt < 4; ++mt)
#pragma unroll
            for (int r = 0; r < 4; ++r) {
                int m = mt * 16 + (lane >> 4) * 4 + r;
                acc[g][mt][r] = ew[(size_t)m * 2048 + g * DD + d0 + col];
            }

#pragma unroll 4
    for (int kc = 0; kc < XH / 32; ++kc) {
        bf16x8 afr[4];
#pragma unroll
        for (int mt = 0; mt < 4; ++mt)
            afr[mt] = *reinterpret_cast<const bf16x8*>(a0 + (size_t)mt * 16 * XH + kc * 32);
#pragma unroll
        for (int g = 0; g < 4; ++g) {
            bf16x8 bfr = *reinterpret_cast<const bf16x8*>(bptr[g] + kc * 32);
#pragma unroll
            for (int mt = 0; mt < 4; ++mt)
                acc[g][mt] = __builtin_amdgcn_mfma_f32_16x16x32_bf16(afr[mt], bfr, acc[g][mt], 0, 0, 0);
        }
    }

    int d = d0 + col;
#pragma unroll
    for (int mt = 0; mt < 4; ++mt)
#pragma unroll
        for (int r = 0; r < 4; ++r) {
            int b = mt * 16 + (lane >> 4) * 4 + r;
            float iv = acc[0][mt][r], fv = acc[1][mt][r], gv = acc[2][mt][r], ov = acc[3][mt][r];
            float cv = c_f32[(size_t)b * DD + d];
            float si = 1.f / (1.f + expf(-iv));
            float sf = 1.f / (1.f + expf(-fv));
            float so = 1.f / (1.f + expf(-ov));
            float cn = sf * cv + si * tanhf(gv);
            float hn = so * tanhf(cn);
            hn_bf[(size_t)b * DD + d] = f2bf(hn);
            if (t < tlen[b]) {
                xh_out[(size_t)b * XH + CC + d] = f2bf(hn);
                c_f32[(size_t)b * DD + d] = cn;
            }
        }
}

// pred = mask ? hn @ W_head + b_head : 0 ; grid 469, 4 waves
__global__ __launch_bounds__(256) void k_head_mfma(const unsigned short* __restrict__ hn_bf,
                                                   const unsigned short* __restrict__ Wt,
                                                   const float* __restrict__ bias,
                                                   const int* __restrict__ tlen, int t,
                                                   float* __restrict__ out_pred) {
    int n0 = blockIdx.x * 64;
    int lane = threadIdx.x & 63, w = threadIdx.x >> 6;
    const unsigned short* a0 = hn_bf + (size_t)(lane & 15) * DD + ((lane >> 4) * 8);
    const unsigned short* b0 = Wt + (size_t)(n0 + w * 16 + (lane & 15)) * DD + ((lane >> 4) * 8);
    f32x4 acc[4];
#pragma unroll
    for (int mt = 0; mt < 4; ++mt) acc[mt] = (f32x4){0.f, 0.f, 0.f, 0.f};
    mm4<DD, DD>(a0, b0, DD, acc);
    int v = n0 + w * 16 + (lane & 15);
    if (v >= VV) return;
    float bv = bias[v];
#pragma unroll
    for (int mt = 0; mt < 4; ++mt)
#pragma unroll
        for (int r = 0; r < 4; ++r) {
            int b = mt * 16 + (lane >> 4) * 4 + r;
            bool act = t < tlen[b];
            out_pred[(size_t)b * TT * VV + (size_t)t * VV + v] = act ? (acc[mt][r] + bv) : 0.f;
        }
}

extern "C" void kernel_launch(void* const* d_in, const int* in_sizes, int n_in,
                              void* d_out, int out_size, void* d_ws, size_t ws_size,
                              hipStream_t stream) {
    const float* enc     = (const float*)d_in[0];
    const int*   text    = (const int*)d_in[1];
    const int*   lens    = (const int*)d_in[2];
    const float* W_init_h = (const float*)d_in[3];
    const float* b_init_h = (const float*)d_in[4];
    const float* W_init_c = (const float*)d_in[5];
    const float* b_init_c = (const float*)d_in[6];
    const float* W_en    = (const float*)d_in[7];
    const float* b_en    = (const float*)d_in[8];
    const float* W_de    = (const float*)d_in[9];
    const float* b_de    = (const float*)d_in[10];
    const float* W_at    = (const float*)d_in[11];
    const float* b_at    = (const float*)d_in[12];
    const float* W_gate  = (const float*)d_in[13];
    const float* b_gate  = (const float*)d_in[14];
    const float* W_ih    = (const float*)d_in[15];
    const float* b_ih    = (const float*)d_in[16];
    const float* W_hh    = (const float*)d_in[17];
    const float* b_hh    = (const float*)d_in[18];
    const float* embed   = (const float*)d_in[19];
    const float* W_head  = (const float*)d_in[20];
    const float* b_head  = (const float*)d_in[21];

    float* outf = (float*)d_out;
    float* out_pred = outf;                               // B*T*V
    float* out_text = outf + (size_t)BB * TT * VV;        // B*L
    float* out_tlen = out_text + BB * LL;                 // B
    float* out_attn = out_tlen + BB;                      // B*T*P
    float* out_idx  = out_attn + (size_t)BB * TT * PP;    // B

    // ---- workspace layout ----
    char* wsb = (char*)d_ws;
    int* idx  = (int*)wsb;
    int* tlen = idx + 64;
    int* ts   = tlen + 64;              // 64*32
    float* fw = (float*)(wsb + 16384);
    float* mean  = fw;  fw += (size_t)BB * CC;
    float* c_f32 = fw;  fw += (size_t)BB * DD;
    float* en    = fw;  fw += (size_t)BB * PP * AA;
    float* de    = fw;  fw += (size_t)BB * AA;
    float* alpha = fw;  fw += (size_t)BB * PP;
    float* ctx   = fw;  fw += (size_t)BB * CC;
    float* embW  = fw;  fw += (size_t)TT * BB * 2048;
    unsigned short* us = (unsigned short*)fw;
    unsigned short* xh_bf   = us;  us += (size_t)BB * XH;
    unsigned short* hn_bf   = us;  us += (size_t)BB * DD;
    unsigned short* emb_all = us;  us += (size_t)TT * BB * EE;
    unsigned short* enc_bf  = us;  us += (size_t)BB * PP * CC;
    unsigned short* Wt_en   = us;  us += (size_t)AA * CC;
    unsigned short* Wt_de   = us;  us += (size_t)AA * DD;
    unsigned short* Wt_gate = us;  us += (size_t)CC * DD;
    unsigned short* Wt_emb  = us;  us += (size_t)2048 * EE;
    unsigned short* Wt_ihh  = us;  us += (size_t)2048 * XH;
    unsigned short* Wt_head = us;  us += (size_t)VPAD * DD;

    // ---- setup ----
    k_mean<<<dim3(BB, CC / 256), 256, 0, stream>>>(enc, mean);
    k_sort<<<1, 64, 0, stream>>>(text, lens, idx, tlen, ts, out_text, out_tlen, out_idx);
    k_init<<<dim3(BB, DD / 256), 256, 0, stream>>>(mean, W_init_h, b_init_h, W_init_c, b_init_c, xh_bf, c_f32);
    k_cvtenc<<<BB * PP, 256, 0, stream>>>(enc, idx, enc_bf);

    dim3 tb(32, 8);
    k_transcvt<<<dim3(AA / 32, CC / 32), tb, 0, stream>>>(W_en, CC, AA, Wt_en, CC, AA);
    k_transcvt<<<dim3(AA / 32, DD / 32), tb, 0, stream>>>(W_de, DD, AA, Wt_de, DD, AA);
    k_transcvt<<<dim3(CC / 32, DD / 32), tb, 0, stream>>>(W_gate, DD, CC, Wt_gate, DD, CC);
    k_transcvt<<<dim3(CC / 32, CC / 32), tb, 0, stream>>>(W_ih, CC, 2048, Wt_ihh, XH, 2048);
    k_transcvt<<<dim3(CC / 32, DD / 32), tb, 0, stream>>>(W_hh, DD, 2048, Wt_ihh + CC, XH, 2048);
    k_transcvt<<<dim3(CC / 32, DD / 32), tb, 0, stream>>>(W_ih + (size_t)CC * 2048, DD, 2048, Wt_emb, EE, 2048);
    k_transcvt<<<dim3(VPAD / 32, DD / 32), tb, 0, stream>>>(W_head, DD, VV, Wt_head, DD, VPAD);

    k_emball<<<TT * BB, 256, 0, stream>>>(embed, ts, emb_all);
    k_embw<<<dim3(TT, 2048 / 64), 256, 0, stream>>>(emb_all, Wt_emb, b_ih, b_hh, embW);
    k_enattn_mfma<<<PP, 256, 0, stream>>>(enc_bf, Wt_en, b_en, en);

    // ---- decode loop ----
    for (int t = 0; t < TT; ++t) {
        k_de_mfma<<<AA / 16, 64, 0, stream>>>(xh_bf, Wt_de, b_de, de);
        k_score<<<BB, 256, 0, stream>>>(en, de, W_at, b_at, tlen, t, alpha, out_attn);
        k_ctx<<<BB, 256, 0, stream>>>(enc_bf, alpha, ctx);
        k_gatex_mfma<<<CC / 16, 64, 0, stream>>>(xh_bf, Wt_gate, b_gate, ctx);
        k_gateslstm<<<DD / 16, 64, 0, stream>>>(xh_bf, Wt_ihh, embW, tlen, t, xh_bf, c_f32, hn_bf);
        k_head_mfma<<<VPAD / 64, 256, 0, stream>>>(hn_bf, Wt_head, b_head, tlen, t, out_pred);
    }
}

// Round 5
// 3090.716 us; speedup vs baseline: 6.2951x; 1.3226x over previous
//
#include <hip/hip_runtime.h>
#include <hip/hip_bf16.h>
#include <math.h>

#define BB 64
#define PP 196
#define CC 2048
#define DD 512
#define AA 512
#define EE 512
#define VV 30000
#define VPAD 30016
#define LL 32
#define TT 31
#define XH 2560   // [ctx*gate (2048) | h (512)]
#define HEADBLK 469  // VPAD/64

typedef short bf16x8 __attribute__((ext_vector_type(8)));
typedef float f32x4 __attribute__((ext_vector_type(4)));

__device__ inline unsigned short f2bf(float x) {
    __hip_bfloat16 h = __float2bfloat16(x);
    return __builtin_bit_cast(unsigned short, h);
}
__device__ inline float bf2f(unsigned short u) {
    unsigned int x = ((unsigned int)u) << 16;
    return __builtin_bit_cast(float, x);
}

// MFMA core: acc[mt] (mt=0..3 m-tiles of 16 rows) over K; a0/b0 pre-offset per lane.
template<int K, int LDA>
__device__ inline void mm4(const unsigned short* __restrict__ a0,
                           const unsigned short* __restrict__ b0,
                           f32x4 acc[4]) {
#pragma unroll
    for (int kc = 0; kc < K / 32; ++kc) {
        bf16x8 bfr = *reinterpret_cast<const bf16x8*>(b0 + kc * 32);
#pragma unroll
        for (int mt = 0; mt < 4; ++mt) {
            bf16x8 afr = *reinterpret_cast<const bf16x8*>(a0 + (size_t)mt * 16 * LDA + kc * 32);
            acc[mt] = __builtin_amdgcn_mfma_f32_16x16x32_bf16(afr, bfr, acc[mt], 0, 0, 0);
        }
    }
}

// ---------- setup kernels ----------

__global__ void k_sort(const int* __restrict__ text, const int* __restrict__ lens,
                       int* __restrict__ idx, int* __restrict__ inv, int* __restrict__ tlen,
                       int* __restrict__ ts,
                       float* __restrict__ out_text, float* __restrict__ out_tlen,
                       float* __restrict__ out_idx) {
    int j = threadIdx.x;
    __shared__ int key[BB];
    __shared__ int sidx[BB];
    key[j] = lens[j];
    __syncthreads();
    int kj = key[j];
    int pos = 0;
    for (int q = 0; q < BB; ++q) {
        int kq = key[q];
        if (kq > kj || (kq == kj && q < j)) pos++;
    }
    sidx[pos] = j;
    __syncthreads();
    int src = sidx[j];
    idx[j] = src;
    inv[src] = j;
    int tl = key[src] - 1;
    tlen[j] = tl;
    out_idx[j] = (float)src;
    out_tlen[j] = (float)tl;
    for (int l = 0; l < LL; ++l) {
        int tok = text[src * LL + l];
        ts[j * LL + l] = tok;
        out_text[j * LL + l] = (float)tok;
    }
}

// sorted gather + f32->bf16: enc_bf[bs*196+p][c] = bf16(enc[idx[bs]][p][c]); grid 12544
__global__ __launch_bounds__(256) void k_cvtenc(const float* __restrict__ enc, const int* __restrict__ idx,
                                                unsigned short* __restrict__ enc_bf) {
    int row = blockIdx.x;           // bs*196+p
    int bs = row / PP, p = row - bs * PP;
    int c0 = threadIdx.x * 8;
    const float* src = enc + ((size_t)idx[bs] * PP + p) * CC + c0;
    f32x4 lo = *reinterpret_cast<const f32x4*>(src);
    f32x4 hi = *reinterpret_cast<const f32x4*>(src + 4);
    unsigned short* dst = enc_bf + (size_t)row * CC + c0;
    bf16x8 v;
    v[0] = (short)f2bf(lo[0]); v[1] = (short)f2bf(lo[1]);
    v[2] = (short)f2bf(lo[2]); v[3] = (short)f2bf(lo[3]);
    v[4] = (short)f2bf(hi[0]); v[5] = (short)f2bf(hi[1]);
    v[6] = (short)f2bf(hi[2]); v[7] = (short)f2bf(hi[3]);
    *reinterpret_cast<bf16x8*>(dst) = v;
}

// mean_bf[b][c] (orig order) from sorted enc_bf; grid (64, 8), 32 c-lanes x 8 p-groups
__global__ __launch_bounds__(256) void k_meanbf(const unsigned short* __restrict__ enc_bf,
                                                const int* __restrict__ inv,
                                                unsigned short* __restrict__ mean_bf) {
    int b = blockIdx.x;
    int lane = threadIdx.x & 31, pg = threadIdx.x >> 5;
    int c0 = blockIdx.y * 256 + lane * 8;
    const unsigned short* img = enc_bf + (size_t)inv[b] * PP * CC + c0;
    float s[8] = {0.f, 0.f, 0.f, 0.f, 0.f, 0.f, 0.f, 0.f};
    for (int p = pg; p < PP; p += 8) {
        bf16x8 v = *reinterpret_cast<const bf16x8*>(img + (size_t)p * CC);
#pragma unroll
        for (int j = 0; j < 8; ++j) s[j] += bf2f((unsigned short)v[j]);
    }
    __shared__ float red[8][256];
#pragma unroll
    for (int j = 0; j < 8; ++j) red[pg][lane * 8 + j] = s[j];
    __syncthreads();
    int c = threadIdx.x;
    float tt = 0.f;
#pragma unroll
    for (int g = 0; g < 8; ++g) tt += red[g][c];
    mean_bf[(size_t)b * CC + blockIdx.y * 256 + c] = f2bf(tt * (1.0f / PP));
}

// h0/c0 via MFMA: grid 64 x 64thr; blocks 0..31 -> h, 32..63 -> c
__global__ __launch_bounds__(64) void k_init_mfma(const unsigned short* __restrict__ mean_bf,
                                                  const unsigned short* __restrict__ Wt_ih,
                                                  const unsigned short* __restrict__ Wt_ic,
                                                  const float* __restrict__ bh, const float* __restrict__ bc,
                                                  unsigned short* __restrict__ xh_bf, float* __restrict__ c_f32) {
    int isC = blockIdx.x >= 32;
    int n0 = (blockIdx.x & 31) * 16;
    int lane = threadIdx.x;
    const unsigned short* Wt = isC ? Wt_ic : Wt_ih;
    const unsigned short* a0 = mean_bf + (size_t)(lane & 15) * CC + ((lane >> 4) * 8);
    const unsigned short* b0 = Wt + (size_t)(n0 + (lane & 15)) * CC + ((lane >> 4) * 8);
    f32x4 acc[4];
#pragma unroll
    for (int mt = 0; mt < 4; ++mt) acc[mt] = (f32x4){0.f, 0.f, 0.f, 0.f};
    mm4<CC, CC>(a0, b0, acc);
    int n = n0 + (lane & 15);
    float bv = (isC ? bc : bh)[n];
#pragma unroll
    for (int mt = 0; mt < 4; ++mt)
#pragma unroll
        for (int r = 0; r < 4; ++r) {
            int m = mt * 16 + (lane >> 4) * 4 + r;
            float val = acc[mt][r] + bv;
            if (isC) c_f32[(size_t)m * DD + n] = val;
            else     xh_bf[(size_t)m * XH + CC + n] = f2bf(val);
        }
}

// transpose+convert: dst[n][k] = bf16(src[k][n]); n >= N -> 0 ; grid (Npad/32, K/32), block (32,8)
__global__ __launch_bounds__(256) void k_transcvt(const float* __restrict__ src, int K, int N,
                                                  unsigned short* __restrict__ dst, int dstStride, int Npad) {
    __shared__ float t[32][33];
    int n0 = blockIdx.x * 32, k0 = blockIdx.y * 32;
    int tx = threadIdx.x, ty = threadIdx.y;
#pragma unroll
    for (int r = 0; r < 4; ++r) {
        int k = k0 + ty + r * 8;
        int n = n0 + tx;
        t[ty + r * 8][tx] = (n < N) ? src[(size_t)k * N + n] : 0.f;
    }
    __syncthreads();
#pragma unroll
    for (int r = 0; r < 4; ++r) {
        int n = n0 + ty + r * 8;
        int k = k0 + tx;
        if (n < Npad) dst[(size_t)n * dstStride + k] = f2bf(t[tx][ty + r * 8]);
    }
}

// emb_all[(t*64+b)][e] = bf16(embed[ts[b][t]][e]) ; grid TT*BB
__global__ __launch_bounds__(256) void k_emball(const float* __restrict__ embed, const int* __restrict__ ts,
                                                unsigned short* __restrict__ emb_all) {
    int row = blockIdx.x;           // t*64+b
    int t = row >> 6, b = row & 63;
    int tok = ts[b * LL + t];
    int e = threadIdx.x * 2;
    const float* src = embed + (size_t)tok * EE + e;
    unsigned short* dst = emb_all + (size_t)row * EE + e;
    dst[0] = f2bf(src[0]);
    dst[1] = f2bf(src[1]);
}

// embW[t][m][n] = emb_all[t*64+m] @ Wt_emb[n] + b_ih[n] + b_hh[n] ; grid (TT, 32), 4 waves
__global__ __launch_bounds__(256) void k_embw(const unsigned short* __restrict__ emb_all,
                                              const unsigned short* __restrict__ Wt_emb,
                                              const float* __restrict__ bih, const float* __restrict__ bhh,
                                              float* __restrict__ embW) {
    int tstep = blockIdx.x;
    int n0 = blockIdx.y * 64;
    int lane = threadIdx.x & 63, w = threadIdx.x >> 6;
    const unsigned short* a0 = emb_all + ((size_t)tstep * 64 + (lane & 15)) * EE + ((lane >> 4) * 8);
    const unsigned short* b0 = Wt_emb + (size_t)(n0 + w * 16 + (lane & 15)) * EE + ((lane >> 4) * 8);
    f32x4 acc[4];
#pragma unroll
    for (int mt = 0; mt < 4; ++mt) acc[mt] = (f32x4){0.f, 0.f, 0.f, 0.f};
    mm4<EE, EE>(a0, b0, acc);
    int n = n0 + w * 16 + (lane & 15);
    float bv = bih[n] + bhh[n];
#pragma unroll
    for (int mt = 0; mt < 4; ++mt)
#pragma unroll
        for (int r = 0; r < 4; ++r) {
            int m = mt * 16 + (lane >> 4) * 4 + r;
            embW[((size_t)tstep * 64 + m) * 2048 + n] = acc[mt][r] + bv;
        }
}

// en = enc_bf(sorted) @ W_en + b_en -> bf16 ; grid 196, 4 waves, N=512 per block
__global__ __launch_bounds__(256) void k_enattn_mfma(const unsigned short* __restrict__ enc_bf,
                                                     const unsigned short* __restrict__ Wt,
                                                     const float* __restrict__ bias,
                                                     unsigned short* __restrict__ en_bf) {
    int m0 = blockIdx.x * 64;
    int lane = threadIdx.x & 63, w = threadIdx.x >> 6;
    const unsigned short* a0 = enc_bf + (size_t)(m0 + (lane & 15)) * CC + ((lane >> 4) * 8);
    const unsigned short* bptr[8];
#pragma unroll
    for (int nt = 0; nt < 8; ++nt) {
        int rowB = nt * 64 + w * 16 + (lane & 15);
        bptr[nt] = Wt + (size_t)rowB * CC + ((lane >> 4) * 8);
    }
    f32x4 acc[4][8];
#pragma unroll
    for (int mt = 0; mt < 4; ++mt)
#pragma unroll
        for (int nt = 0; nt < 8; ++nt) acc[mt][nt] = (f32x4){0.f, 0.f, 0.f, 0.f};

    for (int kc = 0; kc < CC / 32; ++kc) {
        bf16x8 afr[4];
#pragma unroll
        for (int mt = 0; mt < 4; ++mt)
            afr[mt] = *reinterpret_cast<const bf16x8*>(a0 + (size_t)mt * 16 * CC + kc * 32);
#pragma unroll
        for (int nt = 0; nt < 8; ++nt) {
            bf16x8 bfr = *reinterpret_cast<const bf16x8*>(bptr[nt] + kc * 32);
#pragma unroll
            for (int mt = 0; mt < 4; ++mt)
                acc[mt][nt] = __builtin_amdgcn_mfma_f32_16x16x32_bf16(afr[mt], bfr, acc[mt][nt], 0, 0, 0);
        }
    }
#pragma unroll
    for (int nt = 0; nt < 8; ++nt) {
        int n = nt * 64 + w * 16 + (lane & 15);
        float bv = bias[n];
#pragma unroll
        for (int mt = 0; mt < 4; ++mt)
#pragma unroll
            for (int r = 0; r < 4; ++r) {
                int m = m0 + mt * 16 + (lane >> 4) * 4 + r;
                en_bf[(size_t)m * AA + n] = f2bf(acc[mt][nt][r] + bv);
            }
    }
}

// ---------- per-step kernels ----------

// de only (t=0 bootstrap): grid 8, 4 waves x 16 cols
__global__ __launch_bounds__(256) void k_de0(const unsigned short* __restrict__ xh_bf,
                                             const unsigned short* __restrict__ Wt,
                                             const float* __restrict__ bias, float* __restrict__ de) {
    int lane = threadIdx.x & 63, w = threadIdx.x >> 6;
    int n0 = (blockIdx.x * 4 + w) * 16;
    const unsigned short* a0 = xh_bf + CC + (size_t)(lane & 15) * XH + ((lane >> 4) * 8);
    const unsigned short* b0 = Wt + (size_t)(n0 + (lane & 15)) * DD + ((lane >> 4) * 8);
    f32x4 acc[4];
#pragma unroll
    for (int mt = 0; mt < 4; ++mt) acc[mt] = (f32x4){0.f, 0.f, 0.f, 0.f};
    mm4<DD, XH>(a0, b0, acc);
    int n = n0 + (lane & 15);
    float bv = bias[n];
#pragma unroll
    for (int mt = 0; mt < 4; ++mt)
#pragma unroll
        for (int r = 0; r < 4; ++r) {
            int m = mt * 16 + (lane >> 4) * 4 + r;
            de[(size_t)m * AA + n] = acc[mt][r] + bv;
        }
}

// scores + softmax; en is bf16 ; one block per b
__global__ __launch_bounds__(256) void k_score(const unsigned short* __restrict__ en_bf,
                                               const float* __restrict__ de,
                                               const float* __restrict__ Wat, const float* __restrict__ bat,
                                               const int* __restrict__ tlen, int t,
                                               float* __restrict__ alpha, float* __restrict__ out_attn) {
    int b = blockIdx.x;
    int tid = threadIdx.x;
    __shared__ float deL[AA];
    __shared__ float watL[AA];
    __shared__ float red[256];
    deL[tid] = de[(size_t)b * AA + tid];
    deL[tid + 256] = de[(size_t)b * AA + 256 + tid];
    watL[tid] = Wat[tid];
    watL[tid + 256] = Wat[tid + 256];
    __syncthreads();
    float s0 = 0.f, s1 = 0.f;
    if (tid < PP) {
        const unsigned short* er = en_bf + ((size_t)b * PP + tid) * AA;
#pragma unroll 2
        for (int a16 = 0; a16 < AA / 16; ++a16) {
            bf16x8 v0 = *reinterpret_cast<const bf16x8*>(er + a16 * 16);
            bf16x8 v1 = *reinterpret_cast<const bf16x8*>(er + a16 * 16 + 8);
#pragma unroll
            for (int j = 0; j < 8; ++j) {
                float u0 = fmaxf(bf2f((unsigned short)v0[j]) + deL[a16 * 16 + j], 0.f);
                float u1 = fmaxf(bf2f((unsigned short)v1[j]) + deL[a16 * 16 + 8 + j], 0.f);
                s0 = fmaf(u0, watL[a16 * 16 + j], s0);
                s1 = fmaf(u1, watL[a16 * 16 + 8 + j], s1);
            }
        }
    }
    float s = s0 + s1 + bat[0];
    red[tid] = (tid < PP) ? s : -3.4e38f;
    __syncthreads();
    for (int st = 128; st > 0; st >>= 1) {
        if (tid < st) red[tid] = fmaxf(red[tid], red[tid + st]);
        __syncthreads();
    }
    float m = red[0];
    __syncthreads();
    float e = (tid < PP) ? expf(s - m) : 0.f;
    red[tid] = e;
    __syncthreads();
    for (int st = 128; st > 0; st >>= 1) {
        if (tid < st) red[tid] += red[tid + st];
        __syncthreads();
    }
    float inv = 1.0f / red[0];
    if (tid < PP) {
        float al = e * inv;
        alpha[(size_t)b * PP + tid] = al;
        bool act = t < tlen[b];
        out_attn[((size_t)b * TT + t) * PP + tid] = act ? al : 0.f;
    }
}

// ctx: grid (64, 8); 32 c-lanes x 8 p-groups, LDS reduce
__global__ __launch_bounds__(256) void k_ctx(const unsigned short* __restrict__ enc_bf,
                                             const float* __restrict__ alpha, float* __restrict__ ctx) {
    int b = blockIdx.x;
    int lane = threadIdx.x & 31, pg = threadIdx.x >> 5;
    int c0 = blockIdx.y * 256 + lane * 8;
    __shared__ float al[PP];
    if (threadIdx.x < PP) al[threadIdx.x] = alpha[(size_t)b * PP + threadIdx.x];
    __syncthreads();
    const unsigned short* img = enc_bf + (size_t)b * PP * CC + c0;
    float s[8] = {0.f, 0.f, 0.f, 0.f, 0.f, 0.f, 0.f, 0.f};
    for (int p = pg; p < PP; p += 8) {
        float a = al[p];
        bf16x8 v = *reinterpret_cast<const bf16x8*>(img + (size_t)p * CC);
#pragma unroll
        for (int j = 0; j < 8; ++j) s[j] = fmaf(a, bf2f((unsigned short)v[j]), s[j]);
    }
    __shared__ float red[8][256];
#pragma unroll
    for (int j = 0; j < 8; ++j) red[pg][lane * 8 + j] = s[j];
    __syncthreads();
    int c = threadIdx.x;
    float tt = 0.f;
#pragma unroll
    for (int g = 0; g < 8; ++g) tt += red[g][c];
    ctx[(size_t)b * CC + blockIdx.y * 256 + c] = tt;
}

// gate = sigmoid(h @ W_gate + b); xh[ctxg] = bf16(ctx * gate) ; 1-wave blocks, grid 128
__global__ __launch_bounds__(64) void k_gatex_mfma(unsigned short* __restrict__ xh_bf,
                                                   const unsigned short* __restrict__ Wt,
                                                   const float* __restrict__ bias,
                                                   const float* __restrict__ ctx) {
    int n0 = blockIdx.x * 16;
    int lane = threadIdx.x;
    const unsigned short* a0 = xh_bf + CC + (size_t)(lane & 15) * XH + ((lane >> 4) * 8);
    const unsigned short* b0 = Wt + (size_t)(n0 + (lane & 15)) * DD + ((lane >> 4) * 8);
    f32x4 acc[4];
#pragma unroll
    for (int mt = 0; mt < 4; ++mt) acc[mt] = (f32x4){0.f, 0.f, 0.f, 0.f};
    mm4<DD, XH>(a0, b0, acc);
    int n = n0 + (lane & 15);
    float bv = bias[n];
#pragma unroll
    for (int mt = 0; mt < 4; ++mt)
#pragma unroll
        for (int r = 0; r < 4; ++r) {
            int m = mt * 16 + (lane >> 4) * 4 + r;
            float g = 1.f / (1.f + expf(-(acc[mt][r] + bv)));
            xh_bf[(size_t)m * XH + n] = f2bf(ctx[(size_t)m * CC + n] * g);
        }
}

// gates GEMM (acc init from embW) + fused LSTM pointwise ; 1-wave blocks, grid 32
__global__ __launch_bounds__(64) void k_gateslstm(const unsigned short* __restrict__ xh_bf,
                                                  const unsigned short* __restrict__ Wt,
                                                  const float* __restrict__ embW,
                                                  const int* __restrict__ tlen, int t,
                                                  unsigned short* __restrict__ xh_out,
                                                  float* __restrict__ c_f32,
                                                  unsigned short* __restrict__ hn_bf) {
    int d0 = blockIdx.x * 16;
    int lane = threadIdx.x;
    int col = lane & 15;
    const unsigned short* a0 = xh_bf + (size_t)col * XH + ((lane >> 4) * 8);
    const unsigned short* bptr[4];
#pragma unroll
    for (int g = 0; g < 4; ++g)
        bptr[g] = Wt + (size_t)(g * DD + d0 + col) * XH + ((lane >> 4) * 8);

    f32x4 acc[4][4];  // [gate][m-tile]
    const float* ew = embW + (size_t)t * 64 * 2048;
#pragma unroll
    for (int g = 0; g < 4; ++g)
#pragma unroll
        for (int mt = 0; mt < 4; ++mt)
#pragma unroll
            for (int r = 0; r < 4; ++r) {
                int m = mt * 16 + (lane >> 4) * 4 + r;
                acc[g][mt][r] = ew[(size_t)m * 2048 + g * DD + d0 + col];
            }

#pragma unroll 4
    for (int kc = 0; kc < XH / 32; ++kc) {
        bf16x8 afr[4];
#pragma unroll
        for (int mt = 0; mt < 4; ++mt)
            afr[mt] = *reinterpret_cast<const bf16x8*>(a0 + (size_t)mt * 16 * XH + kc * 32);
#pragma unroll
        for (int g = 0; g < 4; ++g) {
            bf16x8 bfr = *reinterpret_cast<const bf16x8*>(bptr[g] + kc * 32);
#pragma unroll
            for (int mt = 0; mt < 4; ++mt)
                acc[g][mt] = __builtin_amdgcn_mfma_f32_16x16x32_bf16(afr[mt], bfr, acc[g][mt], 0, 0, 0);
        }
    }

    int d = d0 + col;
#pragma unroll
    for (int mt = 0; mt < 4; ++mt)
#pragma unroll
        for (int r = 0; r < 4; ++r) {
            int b = mt * 16 + (lane >> 4) * 4 + r;
            float iv = acc[0][mt][r], fv = acc[1][mt][r], gv = acc[2][mt][r], ov = acc[3][mt][r];
            float cv = c_f32[(size_t)b * DD + d];
            float si = 1.f / (1.f + expf(-iv));
            float sf = 1.f / (1.f + expf(-fv));
            float so = 1.f / (1.f + expf(-ov));
            float cn = sf * cv + si * tanhf(gv);
            float hn = so * tanhf(cn);
            hn_bf[(size_t)b * DD + d] = f2bf(hn);
            if (t < tlen[b]) {
                xh_out[(size_t)b * XH + CC + d] = f2bf(hn);
                c_f32[(size_t)b * DD + d] = cn;
            }
        }
}

// head (blocks 0..468) + de for next step (blocks 469..476)
__global__ __launch_bounds__(256) void k_head_de(const unsigned short* __restrict__ hn_bf,
                                                 const unsigned short* __restrict__ Wt_head,
                                                 const float* __restrict__ b_head,
                                                 const unsigned short* __restrict__ xh_bf,
                                                 const unsigned short* __restrict__ Wt_de,
                                                 const float* __restrict__ b_de,
                                                 const int* __restrict__ tlen, int t,
                                                 float* __restrict__ out_pred, float* __restrict__ de) {
    int lane = threadIdx.x & 63, w = threadIdx.x >> 6;
    if (blockIdx.x < HEADBLK) {
        int n0 = blockIdx.x * 64;
        const unsigned short* a0 = hn_bf + (size_t)(lane & 15) * DD + ((lane >> 4) * 8);
        const unsigned short* b0 = Wt_head + (size_t)(n0 + w * 16 + (lane & 15)) * DD + ((lane >> 4) * 8);
        f32x4 acc[4];
#pragma unroll
        for (int mt = 0; mt < 4; ++mt) acc[mt] = (f32x4){0.f, 0.f, 0.f, 0.f};
        mm4<DD, DD>(a0, b0, acc);
        int v = n0 + w * 16 + (lane & 15);
        if (v >= VV) return;
        float bv = b_head[v];
#pragma unroll
        for (int mt = 0; mt < 4; ++mt)
#pragma unroll
            for (int r = 0; r < 4; ++r) {
                int b = mt * 16 + (lane >> 4) * 4 + r;
                bool act = t < tlen[b];
                out_pred[(size_t)b * TT * VV + (size_t)t * VV + v] = act ? (acc[mt][r] + bv) : 0.f;
            }
    } else {
        int n0 = ((blockIdx.x - HEADBLK) * 4 + w) * 16;
        const unsigned short* a0 = xh_bf + CC + (size_t)(lane & 15) * XH + ((lane >> 4) * 8);
        const unsigned short* b0 = Wt_de + (size_t)(n0 + (lane & 15)) * DD + ((lane >> 4) * 8);
        f32x4 acc[4];
#pragma unroll
        for (int mt = 0; mt < 4; ++mt) acc[mt] = (f32x4){0.f, 0.f, 0.f, 0.f};
        mm4<DD, XH>(a0, b0, acc);
        int n = n0 + (lane & 15);
        float bv = b_de[n];
#pragma unroll
        for (int mt = 0; mt < 4; ++mt)
#pragma unroll
            for (int r = 0; r < 4; ++r) {
                int m = mt * 16 + (lane >> 4) * 4 + r;
                de[(size_t)m * AA + n] = acc[mt][r] + bv;
            }
    }
}

extern "C" void kernel_launch(void* const* d_in, const int* in_sizes, int n_in,
                              void* d_out, int out_size, void* d_ws, size_t ws_size,
                              hipStream_t stream) {
    const float* enc     = (const float*)d_in[0];
    const int*   text    = (const int*)d_in[1];
    const int*   lens    = (const int*)d_in[2];
    const float* W_init_h = (const float*)d_in[3];
    const float* b_init_h = (const float*)d_in[4];
    const float* W_init_c = (const float*)d_in[5];
    const float* b_init_c = (const float*)d_in[6];
    const float* W_en    = (const float*)d_in[7];
    const float* b_en    = (const float*)d_in[8];
    const float* W_de    = (const float*)d_in[9];
    const float* b_de    = (const float*)d_in[10];
    const float* W_at    = (const float*)d_in[11];
    const float* b_at    = (const float*)d_in[12];
    const float* W_gate  = (const float*)d_in[13];
    const float* b_gate  = (const float*)d_in[14];
    const float* W_ih    = (const float*)d_in[15];
    const float* b_ih    = (const float*)d_in[16];
    const float* W_hh    = (const float*)d_in[17];
    const float* b_hh    = (const float*)d_in[18];
    const float* embed   = (const float*)d_in[19];
    const float* W_head  = (const float*)d_in[20];
    const float* b_head  = (const float*)d_in[21];

    float* outf = (float*)d_out;
    float* out_pred = outf;                               // B*T*V
    float* out_text = outf + (size_t)BB * TT * VV;        // B*L
    float* out_tlen = out_text + BB * LL;                 // B
    float* out_attn = out_tlen + BB;                      // B*T*P
    float* out_idx  = out_attn + (size_t)BB * TT * PP;    // B

    // ---- workspace layout ----
    char* wsb = (char*)d_ws;
    int* idx  = (int*)wsb;
    int* inv  = idx + 64;
    int* tlen = inv + 64;
    int* ts   = tlen + 64;              // 64*32
    float* fw = (float*)(wsb + 16384);
    float* c_f32 = fw;  fw += (size_t)BB * DD;
    float* de    = fw;  fw += (size_t)BB * AA;
    float* alpha = fw;  fw += (size_t)BB * PP;
    float* ctx   = fw;  fw += (size_t)BB * CC;
    float* embW  = fw;  fw += (size_t)TT * BB * 2048;
    unsigned short* us = (unsigned short*)fw;
    unsigned short* mean_bf = us;  us += (size_t)BB * CC;
    unsigned short* xh_bf   = us;  us += (size_t)BB * XH;
    unsigned short* hn_bf   = us;  us += (size_t)BB * DD;
    unsigned short* emb_all = us;  us += (size_t)TT * BB * EE;
    unsigned short* en_bf   = us;  us += (size_t)BB * PP * AA;
    unsigned short* enc_bf  = us;  us += (size_t)BB * PP * CC;
    unsigned short* Wt_en   = us;  us += (size_t)AA * CC;
    unsigned short* Wt_de   = us;  us += (size_t)AA * DD;
    unsigned short* Wt_gate = us;  us += (size_t)CC * DD;
    unsigned short* Wt_emb  = us;  us += (size_t)2048 * EE;
    unsigned short* Wt_ihh  = us;  us += (size_t)2048 * XH;
    unsigned short* Wt_ih0  = us;  us += (size_t)DD * CC;
    unsigned short* Wt_ic0  = us;  us += (size_t)DD * CC;
    unsigned short* Wt_head = us;  us += (size_t)VPAD * DD;

    // ---- setup ----
    k_sort<<<1, 64, 0, stream>>>(text, lens, idx, inv, tlen, ts, out_text, out_tlen, out_idx);
    k_cvtenc<<<BB * PP, 256, 0, stream>>>(enc, idx, enc_bf);
    k_meanbf<<<dim3(BB, CC / 256), 256, 0, stream>>>(enc_bf, inv, mean_bf);

    dim3 tb(32, 8);
    k_transcvt<<<dim3(AA / 32, CC / 32), tb, 0, stream>>>(W_en, CC, AA, Wt_en, CC, AA);
    k_transcvt<<<dim3(AA / 32, DD / 32), tb, 0, stream>>>(W_de, DD, AA, Wt_de, DD, AA);
    k_transcvt<<<dim3(CC / 32, DD / 32), tb, 0, stream>>>(W_gate, DD, CC, Wt_gate, DD, CC);
    k_transcvt<<<dim3(CC / 32, CC / 32), tb, 0, stream>>>(W_ih, CC, 2048, Wt_ihh, XH, 2048);
    k_transcvt<<<dim3(CC / 32, DD / 32), tb, 0, stream>>>(W_hh, DD, 2048, Wt_ihh + CC, XH, 2048);
    k_transcvt<<<dim3(CC / 32, DD / 32), tb, 0, stream>>>(W_ih + (size_t)CC * 2048, DD, 2048, Wt_emb, EE, 2048);
    k_transcvt<<<dim3(DD / 32, CC / 32), tb, 0, stream>>>(W_init_h, CC, DD, Wt_ih0, CC, DD);
    k_transcvt<<<dim3(DD / 32, CC / 32), tb, 0, stream>>>(W_init_c, CC, DD, Wt_ic0, CC, DD);
    k_transcvt<<<dim3(VPAD / 32, DD / 32), tb, 0, stream>>>(W_head, DD, VV, Wt_head, DD, VPAD);

    k_init_mfma<<<64, 64, 0, stream>>>(mean_bf, Wt_ih0, Wt_ic0, b_init_h, b_init_c, xh_bf, c_f32);
    k_emball<<<TT * BB, 256, 0, stream>>>(embed, ts, emb_all);
    k_embw<<<dim3(TT, 2048 / 64), 256, 0, stream>>>(emb_all, Wt_emb, b_ih, b_hh, embW);
    k_enattn_mfma<<<PP, 256, 0, stream>>>(enc_bf, Wt_en, b_en, en_bf);
    k_de0<<<8, 256, 0, stream>>>(xh_bf, Wt_de, b_de, de);

    // ---- decode loop ----
    for (int t = 0; t < TT; ++t) {
        k_score<<<BB, 256, 0, stream>>>(en_bf, de, W_at, b_at, tlen, t, alpha, out_attn);
        k_ctx<<<dim3(BB, 8), 256, 0, stream>>>(enc_bf, alpha, ctx);
        k_gatex_mfma<<<CC / 16, 64, 0, stream>>>(xh_bf, Wt_gate, b_gate, ctx);
        k_gateslstm<<<DD / 16, 64, 0, stream>>>(xh_bf, Wt_ihh, embW, tlen, t, xh_bf, c_f32, hn_bf);
        k_head_de<<<HEADBLK + 8, 256, 0, stream>>>(hn_bf, Wt_head, b_head, xh_bf, Wt_de, b_de,
                                                   tlen, t, out_pred, de);
    }
}